// Round 15
// baseline (603.506 us; speedup 1.0000x reference)
//
#include <hip/hip_runtime.h>
#include <cstddef>

#define SD 48
#define VOX (SD*SD*SD)        // 110592
#define CSD 24
#define CVOL (CSD*CSD*CSD)    // 13824
#define CST 352               // channel stride in padded bf16 buffer
#define PPL 2500              // 50*50 plane
#define XPBYTES 88000000ull   // 125000*352*2

typedef __attribute__((ext_vector_type(8))) short short8v;
typedef __attribute__((ext_vector_type(4))) short short4v;
typedef __attribute__((ext_vector_type(4))) float float4v;

__device__ __forceinline__ float lrelu(float x, float a){ return x > 0.f ? x : a*x; }

__device__ __forceinline__ unsigned short f2bf(float f){
    unsigned u = __float_as_uint(f);
    unsigned r = (u + 0x7fffu + ((u >> 16) & 1u)) >> 16;
    return (unsigned short)r;
}
__device__ __forceinline__ float bf2f(unsigned short s){
    return __uint_as_float(((unsigned)s) << 16);
}
__device__ __forceinline__ unsigned pk2(float a, float b){
    return (unsigned)f2bf(a) | ((unsigned)f2bf(b) << 16);
}

__device__ __forceinline__ void decode(int v, int &i, int &j, int &k){
    i = v / (SD*SD);
    int r = v - i*(SD*SD);
    j = r / SD;
    k = r - j*SD;
}

// ---------------- Kernel 1: warp + stats + upsample/flow/fixed pack + shell-zero (merged)
// Blocks 0..431: interior voxel work. Blocks 432..920: zero the spatial shell of Xp.
__global__ __launch_bounds__(256) void k_warp_prep(
        const float* __restrict__ moving, const float* __restrict__ fixd,
        const float* __restrict__ flow, const float* __restrict__ context,
        unsigned short* __restrict__ WARPB, float* __restrict__ part,
        unsigned short* __restrict__ Xp)
{
    if (blockIdx.x >= 432){
        int v = (blockIdx.x - 432)*256 + threadIdx.x;
        if (v < 125000){
            int pz = v / 2500, r = v % 2500, py = r / 50, px = r % 50;
            if (pz==0||pz==49||py==0||py==49||px==0||px==49){
                uint4* p = (uint4*)(Xp + (size_t)v*CST);
                uint4 zz = make_uint4(0,0,0,0);
                #pragma unroll
                for (int g=0; g<44; g++) p[g] = zz;
            }
        }
        return;
    }
    int v = blockIdx.x*256 + threadIdx.x;
    int i,j,k; decode(v,i,j,k);
    size_t pvox = (size_t)((i+1)*PPL + (j+1)*50 + (k+1))*CST;

    // ---- trilinear warp of moving at grid+flow
    float f0 = flow[v], f1 = flow[VOX+v], f2v = flow[2*VOX+v];
    float z = (float)i + f0;
    float y = (float)j + f1;
    float x = (float)k + f2v;
    float z0f=floorf(z), y0f=floorf(y), x0f=floorf(x);
    float wz=z-z0f, wy=y-y0f, wx=x-x0f;
    int z0=min(max((int)z0f,0),SD-1), z1=min(max((int)z0f+1,0),SD-1);
    int y0=min(max((int)y0f,0),SD-1), y1=min(max((int)y0f+1,0),SD-1);
    int x0=min(max((int)x0f,0),SD-1), x1=min(max((int)x0f+1,0),SD-1);
    int b000=(z0*SD+y0)*SD+x0, b001=(z0*SD+y0)*SD+x1;
    int b010=(z0*SD+y1)*SD+x0, b011=(z0*SD+y1)*SD+x1;
    int b100=(z1*SD+y0)*SD+x0, b101=(z1*SD+y0)*SD+x1;
    int b110=(z1*SD+y1)*SD+x0, b111=(z1*SD+y1)*SD+x1;
    float w000=(1.f-wz)*(1.f-wy)*(1.f-wx), w001=(1.f-wz)*(1.f-wy)*wx;
    float w010=(1.f-wz)*wy*(1.f-wx),       w011=(1.f-wz)*wy*wx;
    float w100=wz*(1.f-wy)*(1.f-wx),       w101=wz*(1.f-wy)*wx;
    float w110=wz*wy*(1.f-wx),             w111=wz*wy*wx;

    float ow[16];
    float sw=0.f, ssw=0.f, sf=0.f, ssf=0.f;
    #pragma unroll
    for (int c=0;c<16;c++){
        const float* mc = moving + (size_t)c*VOX;
        float o = mc[b000]*w000 + mc[b001]*w001 + mc[b010]*w010 + mc[b011]*w011
                + mc[b100]*w100 + mc[b101]*w101 + mc[b110]*w110 + mc[b111]*w111;
        ow[c] = o;
        sw += o; ssw += o*o;
        float f = fixd[(size_t)c*VOX+v];
        sf += f; ssf += f*f;
    }
    uint4 q0 = make_uint4(pk2(ow[0],ow[1]), pk2(ow[2],ow[3]), pk2(ow[4],ow[5]), pk2(ow[6],ow[7]));
    uint4 q1 = make_uint4(pk2(ow[8],ow[9]), pk2(ow[10],ow[11]), pk2(ow[12],ow[13]), pk2(ow[14],ow[15]));
    uint4* wp = (uint4*)(WARPB + (size_t)v*16);
    wp[0] = q0; wp[1] = q1;

    // ---- context upsample (trilinear 2x, half-pixel, clamped)
    float zc=0.5f*(float)i-0.25f, yc=0.5f*(float)j-0.25f, xc=0.5f*(float)k-0.25f;
    float cz0f=floorf(zc), cy0f=floorf(yc), cx0f=floorf(xc);
    float cwz=zc-cz0f, cwy=yc-cy0f, cwx=xc-cx0f;
    int cz0=min(max((int)cz0f,0),CSD-1), cz1=min(max((int)cz0f+1,0),CSD-1);
    int cy0=min(max((int)cy0f,0),CSD-1), cy1=min(max((int)cy0f+1,0),CSD-1);
    int cx0=min(max((int)cx0f,0),CSD-1), cx1=min(max((int)cx0f+1,0),CSD-1);
    int c000=(cz0*CSD+cy0)*CSD+cx0, c001=(cz0*CSD+cy0)*CSD+cx1;
    int c010=(cz0*CSD+cy1)*CSD+cx0, c011=(cz0*CSD+cy1)*CSD+cx1;
    int c100=(cz1*CSD+cy0)*CSD+cx0, c101=(cz1*CSD+cy0)*CSD+cx1;
    int c110=(cz1*CSD+cy1)*CSD+cx0, c111=(cz1*CSD+cy1)*CSD+cx1;
    float u000=(1.f-cwz)*(1.f-cwy)*(1.f-cwx), u001=(1.f-cwz)*(1.f-cwy)*cwx;
    float u010=(1.f-cwz)*cwy*(1.f-cwx),       u011=(1.f-cwz)*cwy*cwx;
    float u100=cwz*(1.f-cwy)*(1.f-cwx),       u101=cwz*(1.f-cwy)*cwx;
    float u110=cwz*cwy*(1.f-cwx),             u111=cwz*cwy*cwx;

    float oc[32];
    #pragma unroll
    for (int c=0;c<32;c++){
        const float* cc = context + (size_t)c*CVOL;
        oc[c] = cc[c000]*u000 + cc[c001]*u001 + cc[c010]*u010 + cc[c011]*u011
              + cc[c100]*u100 + cc[c101]*u101 + cc[c110]*u110 + cc[c111]*u111;
    }
    uint4* dst = (uint4*)(Xp + pvox);
    #pragma unroll
    for (int g=0; g<4; g++)
        dst[g] = make_uint4(pk2(oc[g*8+0],oc[g*8+1]), pk2(oc[g*8+2],oc[g*8+3]),
                            pk2(oc[g*8+4],oc[g*8+5]), pk2(oc[g*8+6],oc[g*8+7]));
    *(unsigned*)(Xp + pvox + 32) = pk2(f0, f1);
    Xp[pvox + 34] = f2bf(f2v);
    float fx[16];
    #pragma unroll
    for (int c=0;c<16;c++) fx[c] = fixd[(size_t)c*VOX+v];
    uint4* dstF = (uint4*)(Xp + pvox + 160);
    dstF[0] = make_uint4(pk2(fx[0],fx[1]),  pk2(fx[2],fx[3]),  pk2(fx[4],fx[5]),  pk2(fx[6],fx[7]));
    dstF[1] = make_uint4(pk2(fx[8],fx[9]),  pk2(fx[10],fx[11]),pk2(fx[12],fx[13]),pk2(fx[14],fx[15]));

    // ---- stats reduction
    __shared__ float4 red[256];
    int tid=threadIdx.x;
    red[tid] = make_float4(sw,ssw,sf,ssf);
    __syncthreads();
    for (int off=128; off>0; off>>=1){
        if (tid<off){
            float4 a=red[tid], b2=red[tid+off];
            red[tid]=make_float4(a.x+b2.x, a.y+b2.y, a.z+b2.z, a.w+b2.w);
        }
        __syncthreads();
    }
    if (tid==0){
        float4 r=red[0];
        part[blockIdx.x]       = r.x;
        part[432+blockIdx.x]   = r.y;
        part[864+blockIdx.x]   = r.z;
        part[1296+blockIdx.x]  = r.w;
    }
}

// ---------------- Kernel 2: finalize mean/std (deterministic)
__global__ __launch_bounds__(256) void k_stats(const float* __restrict__ part,
                                               float* __restrict__ stats)
{
    int tid=threadIdx.x;
    double acc[4]={0,0,0,0};
    for (int i=tid;i<432;i+=256){
        acc[0]+=part[i]; acc[1]+=part[432+i]; acc[2]+=part[864+i]; acc[3]+=part[1296+i];
    }
    __shared__ double red[256];
    double res[4]={0,0,0,0};
    for (int q=0;q<4;q++){
        red[tid]=acc[q]; __syncthreads();
        for (int off=128;off>0;off>>=1){
            if (tid<off) red[tid]+=red[tid+off];
            __syncthreads();
        }
        res[q]=red[0];
        __syncthreads();
    }
    if (tid==0){
        double N = 16.0*(double)VOX;
        double mw = res[0]/N, mf = res[2]/N;
        double vw = (res[1] - res[0]*res[0]/N)/(N-1.0);
        double vf = (res[3] - res[2]*res[2]/N)/(N-1.0);
        double m = 0.5*(mw+mf);
        double s = 0.5*(sqrt(vw)+sqrt(vf));
        stats[0]=(float)m;
        stats[1]=(float)(1.0/s);
    }
}

// ---------------- Kernel 4: cost volume, all 125 shifts in registers, burst stores
__global__ __launch_bounds__(256) void k_cv(
        const float* __restrict__ fixd, const unsigned short* __restrict__ WARPB,
        const float* __restrict__ stats, unsigned short* __restrict__ Xp)
{
    int v = blockIdx.x*256 + threadIdx.x;
    int i,j,k; decode(v,i,j,k);
    size_t pvox = (size_t)((i+1)*PPL + (j+1)*50 + (k+1))*CST;
    float m = stats[0], inv_s = stats[1];
    float fn[16]; float sfn = 0.f;
    #pragma unroll
    for (int c=0;c<16;c++){ fn[c] = (fixd[(size_t)c*VOX+v]-m)*inv_s; sfn += fn[c]; }
    float scale = inv_s*(1.0f/16.0f);
    float msfn = m*sfn;

    float res[125];
    #pragma unroll
    for (int dz=-2;dz<=2;dz++){
        int zz=i+dz;
        #pragma unroll
        for (int dy=-2;dy<=2;dy++){
            int yy=j+dy;
            #pragma unroll
            for (int dx=-2;dx<=2;dx++){
                int xx=k+dx;
                const int r = (dz+2)*25+(dy+2)*5+(dx+2);
                float o = 0.f;
                if ((unsigned)zz<SD && (unsigned)yy<SD && (unsigned)xx<SD){
                    int vs=(zz*SD+yy)*SD+xx;
                    const short8v* wr = (const short8v*)(WARPB + (size_t)vs*16);
                    short8v wlo = wr[0], whi = wr[1];
                    float d = 0.f;
                    #pragma unroll
                    for (int e=0;e<8;e++) d += fn[e]   * bf2f((unsigned short)wlo[e]);
                    #pragma unroll
                    for (int e=0;e<8;e++) d += fn[8+e] * bf2f((unsigned short)whi[e]);
                    o = lrelu(scale*(d - msfn), 0.05f);
                }
                res[r] = o;
            }
        }
    }
    Xp[pvox + 35] = f2bf(res[0]);
    {
        short4v s4;
        #pragma unroll
        for (int e=0;e<4;e++) s4[e] = (short)f2bf(res[1+e]);
        *(short4v*)(Xp + pvox + 36) = s4;
    }
    #pragma unroll
    for (int g=0; g<15; g++){
        short8v s8;
        #pragma unroll
        for (int e=0;e<8;e++) s8[e] = (short)f2bf(res[5+g*8+e]);
        *(short8v*)(Xp + pvox + 40 + g*8) = s8;
    }
}

// ---------------- Kernel 5: merged weight transform (all 5 convs, one launch)
__device__ __forceinline__ void wb_one(int idx, const float* __restrict__ w,
        unsigned short* __restrict__ dst, int CO, int CIN, int CT)
{
    int e = idx & 7;
    int l = (idx >> 3) & 63;
    int rest = idx >> 9;
    int ct = rest % CT;
    int rest2 = rest / CT;
    int tn = rest2 % 27;
    int chunk = rest2 / 27;
    int dz = tn/9, rr = tn%9, dxx = rr/3, dyy = rr%3;
    int t_orig = dz*9 + dyy*3 + dxx;             // reference [kz][ky][kx]
    int co = ct*16 + (l & 15);
    int cin = chunk*32 + (l >> 4)*8 + e;
    unsigned short v = 0;
    if (co < CO && cin < CIN) v = f2bf(w[((size_t)co*CIN + cin)*27 + t_orig]);
    dst[idx] = v;
}

__global__ __launch_bounds__(256) void k_wb_all(
        const float* __restrict__ w0, const float* __restrict__ w1,
        const float* __restrict__ w2, const float* __restrict__ w3,
        const float* __restrict__ w4,
        unsigned short* __restrict__ Wb0, unsigned short* __restrict__ Wb1,
        unsigned short* __restrict__ Wb2, unsigned short* __restrict__ Wb3,
        unsigned short* __restrict__ Wb4)
{
    const int n0=331776, n1=331776, n2=248832, n3=138240, n4=13824;
    int idx = blockIdx.x*256 + threadIdx.x;
    if (idx < n0){ wb_one(idx, w0, Wb0, 64, 176, 4); return; }
    idx -= n0;
    if (idx < n1){ wb_one(idx, w1, Wb1, 48, 240, 3); return; }
    idx -= n1;
    if (idx < n2){ wb_one(idx, w2, Wb2, 32, 288, 2); return; }
    idx -= n2;
    if (idx < n3){ wb_one(idx, w3, Wb3, 16, 320, 1); return; }
    idx -= n3;
    if (idx < n4){ wb_one(idx, w4, Wb4,  3,  16, 1); return; }
}

// ---------------- Kernel 6: MFMA conv, DEPTH weight ring + T14 reg-staged input
// Block: 128 thr = 2 waves. Tile: x16 (lane&15), y4 (vt), z2 (wave).
// Slab: [4 z][6 y][18 x][32 ch] bf16 = 27648 B, SINGLE buffer.
// T14 async-STAGE: issue global_load->regs for chunk c+1 BEFORE computing chunk
// c (drain hides under ~2900cyc MFMA), ds_write after the read-done barrier.
// +56 VGPR, zero LDS cost (occupancy grid-limited). Ring indices compile-time.
// DEPTH law: D3 for CT>=3 (R11/R13: deeper thrashes L2), D9 for CT<=2 (R11).
template<int CT, int DEPTH, int MODE>
__global__ __launch_bounds__(128) void k_mconv(
        const unsigned short* __restrict__ Xp,
        const unsigned short* __restrict__ Wb,
        const float* __restrict__ bias,
        int nchunks, int ch_base,
        unsigned short* __restrict__ Ydst,
        float* __restrict__ outf,
        const float* __restrict__ flw)
{
    __shared__ unsigned short slab[13824]; // 4*6*18*32
    const int tid = threadIdx.x;
    const int bid0 = blockIdx.x;
    const int bid = (bid0 & 7)*108 + (bid0 >> 3);   // grid 864 = 8*108, bijective
    const int xt = bid % 3, yt = (bid/3) % 12, zt = bid / 36;
    const int x0 = xt*16, y0 = yt*4, z0 = zt*2;
    const int lane = tid & 63, w = tid >> 6;
    const int lx = lane & 15, kb = lane >> 4;

    int voff[14];
    #pragma unroll
    for (int i=0;i<14;i++){
        int u = tid + i*128;
        int p = u >> 2, q = u & 3;
        int sx = p % 18; int pr = p / 18; int sy = pr % 6; int sz = pr / 6;
        sz = min(sz, 3);
        voff[i] = ((z0+sz)*PPL + (y0+sy)*50 + (x0+sx))*CST + q*8;
    }

    float4v acc[4][CT];
    #pragma unroll
    for (int vt=0; vt<4; vt++)
        #pragma unroll
        for (int ct=0; ct<CT; ct++)
            acc[vt][ct] = (float4v){0.f,0.f,0.f,0.f};

    const unsigned short* wl = Wb + (size_t)lane*8;
    const int gmax = nchunks*27 - 1;
    short8v a[DEPTH][CT];
    #pragma unroll
    for (int d=0; d<DEPTH-1; d++)
        #pragma unroll
        for (int ct=0; ct<CT; ct++)
            a[d][ct] = *(const short8v*)(wl + (size_t)min(d,gmax)*(CT*512) + (size_t)ct*512);

    // T14 stage registers (14 x 16B = 56 VGPR)
    uint4 st[14];

    // prologue: load chunk 0 -> regs -> LDS
    {
        const int cb = ch_base;
        #pragma unroll
        for (int i=0;i<14;i++){
            int u = tid + i*128;
            if (i < 13 || u < 1728)
                st[i] = *(const uint4*)(Xp + voff[i] + cb);
        }
        #pragma unroll
        for (int i=0;i<14;i++){
            int u = tid + i*128;
            if (i < 13 || u < 1728)
                *(uint4*)(slab + (size_t)u*8) = st[i];
        }
        __syncthreads();
    }

    for (int chunk=0; chunk<nchunks; chunk++){
        // issue next chunk's loads into regs (drain during this chunk's MFMAs)
        if (chunk+1 < nchunks){
            const int cb = ch_base + (chunk+1)*32;
            #pragma unroll
            for (int i=0;i<14;i++){
                int u = tid + i*128;
                if (i < 13 || u < 1728)
                    st[i] = *(const uint4*)(Xp + voff[i] + cb);
            }
        }

        const int gb = chunk*27;
        #pragma unroll
        for (int dz=0; dz<3; dz++){
            #pragma unroll
            for (int dxx=0; dxx<3; dxx++){
                short8v brow[6];
                #pragma unroll
                for (int yi=0; yi<6; yi++)
                    brow[yi] = *(const short8v*)(slab
                        + (size_t)((((w+dz)*6 + yi)*18 + dxx + lx)*32 + kb*8));
                #pragma unroll
                for (int dyy=0; dyy<3; dyy++){
                    const int t = dz*9 + dxx*3 + dyy;
                    {
                        int g2 = gb + t + (DEPTH-1); g2 = min(g2, gmax);
                        #pragma unroll
                        for (int ct=0; ct<CT; ct++)
                            a[(t+DEPTH-1)%DEPTH][ct] = *(const short8v*)(wl
                                + (size_t)g2*(CT*512) + (size_t)ct*512);
                    }
                    __builtin_amdgcn_s_setprio(1);
                    #pragma unroll
                    for (int vt=0; vt<4; vt++)
                        #pragma unroll
                        for (int ct=0; ct<CT; ct++)
                            acc[vt][ct] = __builtin_amdgcn_mfma_f32_16x16x32_bf16(
                                              a[t%DEPTH][ct], brow[vt+dyy], acc[vt][ct], 0, 0, 0);
                    __builtin_amdgcn_s_setprio(0);
                }
            }
        }

        if (chunk+1 < nchunks){
            __syncthreads();    // all reads of slab done
            #pragma unroll
            for (int i=0;i<14;i++){
                int u = tid + i*128;
                if (i < 13 || u < 1728)
                    *(uint4*)(slab + (size_t)u*8) = st[i];   // waits vmcnt (drained)
            }
            __syncthreads();    // writes visible
        }
    }

    const int x = x0 + lx, z = z0 + w;
    #pragma unroll
    for (int vt=0; vt<4; vt++){
        const int y = y0 + vt;
        const size_t pvox = (size_t)((z+1)*PPL + (y+1)*50 + (x+1))*CST;
        const int vi = (z*SD + y)*SD + x;
        #pragma unroll
        for (int ct=0; ct<CT; ct++){
            if (MODE == 2){
                #pragma unroll
                for (int r=0; r<4; r++){
                    const int co = ct*16 + kb*4 + r;
                    if (co < 3){
                        float vv = acc[vt][ct][r] + bias[co];
                        outf[(size_t)co*VOX + vi] = flw[(size_t)co*VOX + vi] + vv;
                    }
                }
            } else {
                const int co0 = ct*16 + kb*4;
                short4v s4;
                #pragma unroll
                for (int r=0; r<4; r++){
                    float vv = acc[vt][ct][r] + bias[co0+r];
                    float o = lrelu(vv, 0.02f);
                    s4[r] = (short)f2bf(o);
                    if (MODE == 1)
                        outf[(size_t)(co0+r)*VOX + vi] = o;
                }
                *(short4v*)(Ydst + pvox + co0) = s4;
            }
        }
    }
}

extern "C" void kernel_launch(void* const* d_in, const int* in_sizes, int n_in,
                              void* d_out, int out_size, void* d_ws, size_t ws_size,
                              hipStream_t stream) {
    const float* moving  = (const float*)d_in[0];
    const float* fixd    = (const float*)d_in[1];
    const float* flow    = (const float*)d_in[2];
    const float* context = (const float*)d_in[3];
    const float* w0 = (const float*)d_in[4];  const float* b0 = (const float*)d_in[5];
    const float* w1 = (const float*)d_in[6];  const float* b1 = (const float*)d_in[7];
    const float* w2 = (const float*)d_in[8];  const float* b2 = (const float*)d_in[9];
    const float* w3 = (const float*)d_in[10]; const float* b3 = (const float*)d_in[11];
    const float* w4 = (const float*)d_in[12]; const float* b4 = (const float*)d_in[13];

    char* ws = (char*)d_ws;
    unsigned short* Xp    = (unsigned short*)ws;                  // 88.0 MB padded bf16, ch-last
    unsigned short* WARPB = (unsigned short*)(ws + XPBYTES);      // 16*VOX bf16 = 3.54 MB
    float* PART  = (float*)(ws + XPBYTES + 3538944ull);           // 4*432 f32
    float* STATS = (float*)(ws + XPBYTES + 3538944ull + 8192ull);
    unsigned short* Wb0 = (unsigned short*)(ws + XPBYTES + 3538944ull + 9216ull);
    unsigned short* Wb1 = Wb0 + (size_t)331776;   // 6*27*4*512
    unsigned short* Wb2 = Wb1 + (size_t)331776;   // 8*27*3*512
    unsigned short* Wb3 = Wb2 + (size_t)248832;   // 9*27*2*512
    unsigned short* Wb4 = Wb3 + (size_t)138240;   // 10*27*1*512

    float* ctx_out  = (float*)d_out;                  // 16*VOX
    float* flow_out = (float*)d_out + (size_t)16*VOX; // 3*VOX

    k_warp_prep<<<921,256,0,stream>>>(moving, fixd, flow, context, WARPB, PART, Xp);
    k_stats<<<1,256,0,stream>>>(PART, STATS);
    k_cv<<<432,256,0,stream>>>(fixd, WARPB, STATS, Xp);
    k_wb_all<<<4158,256,0,stream>>>(w0, w1, w2, w3, w4, Wb0, Wb1, Wb2, Wb3, Wb4);

    // Per-CT ring-depth law: D3 for CT>=3 (R11/R13), D9 for CT<=2 (R11)
    k_mconv<4,3,0><<<864,128,0,stream>>>(Xp, Wb0, b0, 6,  0,   Xp+176, nullptr, nullptr);
    k_mconv<3,3,0><<<864,128,0,stream>>>(Xp, Wb1, b1, 8,  0,   Xp+240, nullptr, nullptr);
    k_mconv<2,9,0><<<864,128,0,stream>>>(Xp, Wb2, b2, 9,  0,   Xp+288, nullptr, nullptr);
    k_mconv<1,9,1><<<864,128,0,stream>>>(Xp, Wb3, b3, 10, 0,   Xp+320, ctx_out, nullptr);
    k_mconv<1,3,2><<<864,128,0,stream>>>(Xp, Wb4, b4, 1,  320, Xp,     flow_out, flow);
}

// Round 16
// 381.854 us; speedup vs baseline: 1.5805x; 1.5805x over previous
//
#include <hip/hip_runtime.h>
#include <cstddef>

#define SD 48
#define VOX (SD*SD*SD)        // 110592
#define CSD 24
#define CVOL (CSD*CSD*CSD)    // 13824
#define CST 352               // channel stride in padded bf16 buffer
#define PPL 2500              // 50*50 plane
#define XPBYTES 88000000ull   // 125000*352*2

typedef __attribute__((ext_vector_type(8))) short short8v;
typedef __attribute__((ext_vector_type(4))) short short4v;
typedef __attribute__((ext_vector_type(4))) float float4v;

__device__ __forceinline__ float lrelu(float x, float a){ return x > 0.f ? x : a*x; }

__device__ __forceinline__ unsigned short f2bf(float f){
    unsigned u = __float_as_uint(f);
    unsigned r = (u + 0x7fffu + ((u >> 16) & 1u)) >> 16;
    return (unsigned short)r;
}
__device__ __forceinline__ float bf2f(unsigned short s){
    return __uint_as_float(((unsigned)s) << 16);
}
__device__ __forceinline__ unsigned pk2(float a, float b){
    return (unsigned)f2bf(a) | ((unsigned)f2bf(b) << 16);
}

__device__ __forceinline__ void decode(int v, int &i, int &j, int &k){
    i = v / (SD*SD);
    int r = v - i*(SD*SD);
    j = r / SD;
    k = r - j*SD;
}

// ---------------- Kernel 1: warp + stats + upsample/flow/fixed pack + shell-zero (merged)
// Blocks 0..431: interior voxel work. Blocks 432..920: zero the spatial shell of Xp.
__global__ __launch_bounds__(256) void k_warp_prep(
        const float* __restrict__ moving, const float* __restrict__ fixd,
        const float* __restrict__ flow, const float* __restrict__ context,
        unsigned short* __restrict__ WARPB, float* __restrict__ part,
        unsigned short* __restrict__ Xp)
{
    if (blockIdx.x >= 432){
        int v = (blockIdx.x - 432)*256 + threadIdx.x;
        if (v < 125000){
            int pz = v / 2500, r = v % 2500, py = r / 50, px = r % 50;
            if (pz==0||pz==49||py==0||py==49||px==0||px==49){
                uint4* p = (uint4*)(Xp + (size_t)v*CST);
                uint4 zz = make_uint4(0,0,0,0);
                #pragma unroll
                for (int g=0; g<44; g++) p[g] = zz;
            }
        }
        return;
    }
    int v = blockIdx.x*256 + threadIdx.x;
    int i,j,k; decode(v,i,j,k);
    size_t pvox = (size_t)((i+1)*PPL + (j+1)*50 + (k+1))*CST;

    // ---- trilinear warp of moving at grid+flow
    float f0 = flow[v], f1 = flow[VOX+v], f2v = flow[2*VOX+v];
    float z = (float)i + f0;
    float y = (float)j + f1;
    float x = (float)k + f2v;
    float z0f=floorf(z), y0f=floorf(y), x0f=floorf(x);
    float wz=z-z0f, wy=y-y0f, wx=x-x0f;
    int z0=min(max((int)z0f,0),SD-1), z1=min(max((int)z0f+1,0),SD-1);
    int y0=min(max((int)y0f,0),SD-1), y1=min(max((int)y0f+1,0),SD-1);
    int x0=min(max((int)x0f,0),SD-1), x1=min(max((int)x0f+1,0),SD-1);
    int b000=(z0*SD+y0)*SD+x0, b001=(z0*SD+y0)*SD+x1;
    int b010=(z0*SD+y1)*SD+x0, b011=(z0*SD+y1)*SD+x1;
    int b100=(z1*SD+y0)*SD+x0, b101=(z1*SD+y0)*SD+x1;
    int b110=(z1*SD+y1)*SD+x0, b111=(z1*SD+y1)*SD+x1;
    float w000=(1.f-wz)*(1.f-wy)*(1.f-wx), w001=(1.f-wz)*(1.f-wy)*wx;
    float w010=(1.f-wz)*wy*(1.f-wx),       w011=(1.f-wz)*wy*wx;
    float w100=wz*(1.f-wy)*(1.f-wx),       w101=wz*(1.f-wy)*wx;
    float w110=wz*wy*(1.f-wx),             w111=wz*wy*wx;

    float ow[16];
    float sw=0.f, ssw=0.f, sf=0.f, ssf=0.f;
    #pragma unroll
    for (int c=0;c<16;c++){
        const float* mc = moving + (size_t)c*VOX;
        float o = mc[b000]*w000 + mc[b001]*w001 + mc[b010]*w010 + mc[b011]*w011
                + mc[b100]*w100 + mc[b101]*w101 + mc[b110]*w110 + mc[b111]*w111;
        ow[c] = o;
        sw += o; ssw += o*o;
        float f = fixd[(size_t)c*VOX+v];
        sf += f; ssf += f*f;
    }
    uint4 q0 = make_uint4(pk2(ow[0],ow[1]), pk2(ow[2],ow[3]), pk2(ow[4],ow[5]), pk2(ow[6],ow[7]));
    uint4 q1 = make_uint4(pk2(ow[8],ow[9]), pk2(ow[10],ow[11]), pk2(ow[12],ow[13]), pk2(ow[14],ow[15]));
    uint4* wp = (uint4*)(WARPB + (size_t)v*16);
    wp[0] = q0; wp[1] = q1;

    // ---- context upsample (trilinear 2x, half-pixel, clamped)
    float zc=0.5f*(float)i-0.25f, yc=0.5f*(float)j-0.25f, xc=0.5f*(float)k-0.25f;
    float cz0f=floorf(zc), cy0f=floorf(yc), cx0f=floorf(xc);
    float cwz=zc-cz0f, cwy=yc-cy0f, cwx=xc-cx0f;
    int cz0=min(max((int)cz0f,0),CSD-1), cz1=min(max((int)cz0f+1,0),CSD-1);
    int cy0=min(max((int)cy0f,0),CSD-1), cy1=min(max((int)cy0f+1,0),CSD-1);
    int cx0=min(max((int)cx0f,0),CSD-1), cx1=min(max((int)cx0f+1,0),CSD-1);
    int c000=(cz0*CSD+cy0)*CSD+cx0, c001=(cz0*CSD+cy0)*CSD+cx1;
    int c010=(cz0*CSD+cy1)*CSD+cx0, c011=(cz0*CSD+cy1)*CSD+cx1;
    int c100=(cz1*CSD+cy0)*CSD+cx0, c101=(cz1*CSD+cy0)*CSD+cx1;
    int c110=(cz1*CSD+cy1)*CSD+cx0, c111=(cz1*CSD+cy1)*CSD+cx1;
    float u000=(1.f-cwz)*(1.f-cwy)*(1.f-cwx), u001=(1.f-cwz)*(1.f-cwy)*cwx;
    float u010=(1.f-cwz)*cwy*(1.f-cwx),       u011=(1.f-cwz)*cwy*cwx;
    float u100=cwz*(1.f-cwy)*(1.f-cwx),       u101=cwz*(1.f-cwy)*cwx;
    float u110=cwz*cwy*(1.f-cwx),             u111=cwz*cwy*cwx;

    float oc[32];
    #pragma unroll
    for (int c=0;c<32;c++){
        const float* cc = context + (size_t)c*CVOL;
        oc[c] = cc[c000]*u000 + cc[c001]*u001 + cc[c010]*u010 + cc[c011]*u011
              + cc[c100]*u100 + cc[c101]*u101 + cc[c110]*u110 + cc[c111]*u111;
    }
    uint4* dst = (uint4*)(Xp + pvox);
    #pragma unroll
    for (int g=0; g<4; g++)
        dst[g] = make_uint4(pk2(oc[g*8+0],oc[g*8+1]), pk2(oc[g*8+2],oc[g*8+3]),
                            pk2(oc[g*8+4],oc[g*8+5]), pk2(oc[g*8+6],oc[g*8+7]));
    *(unsigned*)(Xp + pvox + 32) = pk2(f0, f1);
    Xp[pvox + 34] = f2bf(f2v);
    float fx[16];
    #pragma unroll
    for (int c=0;c<16;c++) fx[c] = fixd[(size_t)c*VOX+v];
    uint4* dstF = (uint4*)(Xp + pvox + 160);
    dstF[0] = make_uint4(pk2(fx[0],fx[1]),  pk2(fx[2],fx[3]),  pk2(fx[4],fx[5]),  pk2(fx[6],fx[7]));
    dstF[1] = make_uint4(pk2(fx[8],fx[9]),  pk2(fx[10],fx[11]),pk2(fx[12],fx[13]),pk2(fx[14],fx[15]));

    // ---- stats reduction
    __shared__ float4 red[256];
    int tid=threadIdx.x;
    red[tid] = make_float4(sw,ssw,sf,ssf);
    __syncthreads();
    for (int off=128; off>0; off>>=1){
        if (tid<off){
            float4 a=red[tid], b2=red[tid+off];
            red[tid]=make_float4(a.x+b2.x, a.y+b2.y, a.z+b2.z, a.w+b2.w);
        }
        __syncthreads();
    }
    if (tid==0){
        float4 r=red[0];
        part[blockIdx.x]       = r.x;
        part[432+blockIdx.x]   = r.y;
        part[864+blockIdx.x]   = r.z;
        part[1296+blockIdx.x]  = r.w;
    }
}

// ---------------- Kernel 2: finalize mean/std (deterministic)
__global__ __launch_bounds__(256) void k_stats(const float* __restrict__ part,
                                               float* __restrict__ stats)
{
    int tid=threadIdx.x;
    double acc[4]={0,0,0,0};
    for (int i=tid;i<432;i+=256){
        acc[0]+=part[i]; acc[1]+=part[432+i]; acc[2]+=part[864+i]; acc[3]+=part[1296+i];
    }
    __shared__ double red[256];
    double res[4]={0,0,0,0};
    for (int q=0;q<4;q++){
        red[tid]=acc[q]; __syncthreads();
        for (int off=128;off>0;off>>=1){
            if (tid<off) red[tid]+=red[tid+off];
            __syncthreads();
        }
        res[q]=red[0];
        __syncthreads();
    }
    if (tid==0){
        double N = 16.0*(double)VOX;
        double mw = res[0]/N, mf = res[2]/N;
        double vw = (res[1] - res[0]*res[0]/N)/(N-1.0);
        double vf = (res[3] - res[2]*res[2]/N)/(N-1.0);
        double m = 0.5*(mw+mf);
        double s = 0.5*(sqrt(vw)+sqrt(vf));
        stats[0]=(float)m;
        stats[1]=(float)(1.0/s);
    }
}

// ---------------- Kernel 4: cost volume, all 125 shifts in registers, burst stores
__global__ __launch_bounds__(256) void k_cv(
        const float* __restrict__ fixd, const unsigned short* __restrict__ WARPB,
        const float* __restrict__ stats, unsigned short* __restrict__ Xp)
{
    int v = blockIdx.x*256 + threadIdx.x;
    int i,j,k; decode(v,i,j,k);
    size_t pvox = (size_t)((i+1)*PPL + (j+1)*50 + (k+1))*CST;
    float m = stats[0], inv_s = stats[1];
    float fn[16]; float sfn = 0.f;
    #pragma unroll
    for (int c=0;c<16;c++){ fn[c] = (fixd[(size_t)c*VOX+v]-m)*inv_s; sfn += fn[c]; }
    float scale = inv_s*(1.0f/16.0f);
    float msfn = m*sfn;

    float res[125];
    #pragma unroll
    for (int dz=-2;dz<=2;dz++){
        int zz=i+dz;
        #pragma unroll
        for (int dy=-2;dy<=2;dy++){
            int yy=j+dy;
            #pragma unroll
            for (int dx=-2;dx<=2;dx++){
                int xx=k+dx;
                const int r = (dz+2)*25+(dy+2)*5+(dx+2);
                float o = 0.f;
                if ((unsigned)zz<SD && (unsigned)yy<SD && (unsigned)xx<SD){
                    int vs=(zz*SD+yy)*SD+xx;
                    const short8v* wr = (const short8v*)(WARPB + (size_t)vs*16);
                    short8v wlo = wr[0], whi = wr[1];
                    float d = 0.f;
                    #pragma unroll
                    for (int e=0;e<8;e++) d += fn[e]   * bf2f((unsigned short)wlo[e]);
                    #pragma unroll
                    for (int e=0;e<8;e++) d += fn[8+e] * bf2f((unsigned short)whi[e]);
                    o = lrelu(scale*(d - msfn), 0.05f);
                }
                res[r] = o;
            }
        }
    }
    Xp[pvox + 35] = f2bf(res[0]);
    {
        short4v s4;
        #pragma unroll
        for (int e=0;e<4;e++) s4[e] = (short)f2bf(res[1+e]);
        *(short4v*)(Xp + pvox + 36) = s4;
    }
    #pragma unroll
    for (int g=0; g<15; g++){
        short8v s8;
        #pragma unroll
        for (int e=0;e<8;e++) s8[e] = (short)f2bf(res[5+g*8+e]);
        *(short8v*)(Xp + pvox + 40 + g*8) = s8;
    }
}

// ---------------- Kernel 5: merged weight transform (all 5 convs, one launch)
// layout per conv: dst[chunk][tn][ct][lane(64)][8], tn = dz*9+dx*3+dy;
// lane l holds W[co = ct*16 + (l&15)][cin = chunk*32 + (l>>4)*8 + e]
__device__ __forceinline__ void wb_one(int idx, const float* __restrict__ w,
        unsigned short* __restrict__ dst, int CO, int CIN, int CT)
{
    int e = idx & 7;
    int l = (idx >> 3) & 63;
    int rest = idx >> 9;
    int ct = rest % CT;
    int rest2 = rest / CT;
    int tn = rest2 % 27;
    int chunk = rest2 / 27;
    int dz = tn/9, rr = tn%9, dxx = rr/3, dyy = rr%3;
    int t_orig = dz*9 + dyy*3 + dxx;             // reference [kz][ky][kx]
    int co = ct*16 + (l & 15);
    int cin = chunk*32 + (l >> 4)*8 + e;
    unsigned short v = 0;
    if (co < CO && cin < CIN) v = f2bf(w[((size_t)co*CIN + cin)*27 + t_orig]);
    dst[idx] = v;
}

__global__ __launch_bounds__(256) void k_wb_all(
        const float* __restrict__ w0, const float* __restrict__ w1,
        const float* __restrict__ w2, const float* __restrict__ w3,
        const float* __restrict__ w4,
        unsigned short* __restrict__ Wb0, unsigned short* __restrict__ Wb1,
        unsigned short* __restrict__ Wb2, unsigned short* __restrict__ Wb3,
        unsigned short* __restrict__ Wb4)
{
    const int n0=331776, n1=331776, n2=248832, n3=138240, n4=13824;
    int idx = blockIdx.x*256 + threadIdx.x;
    if (idx < n0){ wb_one(idx, w0, Wb0, 64, 176, 4); return; }
    idx -= n0;
    if (idx < n1){ wb_one(idx, w1, Wb1, 48, 240, 3); return; }
    idx -= n1;
    if (idx < n2){ wb_one(idx, w2, Wb2, 32, 288, 2); return; }
    idx -= n2;
    if (idx < n3){ wb_one(idx, w3, Wb3, 16, 320, 1); return; }
    idx -= n3;
    if (idx < n4){ wb_one(idx, w4, Wb4,  3,  16, 1); return; }
}

// ---------------- Kernel 6: MFMA conv, per-tap DEPTH ring
// Block: 128 thr = 2 waves. Tile: x16 (lane&15), y4 (vt), z2 (wave).
// Slab: [4 z][6 y][18 x][32 ch] bf16 = 27648 B single-buffered.
// Ring a[DEPTH][CT], flat tap stream (27%DEPTH==0 -> slot continuity across
// chunks), prefetch tap t+DEPTH-1; all ring indices compile-time (rule #20).
// Empirical DEPTH law (R11/R13): D3 for CT>=3 (deeper thrashes L2: FETCH
// 42->62MB, dur +15%); D9 for CT<=2. T5 setprio around MFMAs.
// R15 lesson: T14 reg-staging regresses (compiler sinks loads; FETCH 3x) —
// global_load_lds staging with exposed drain is the best-known structure here.
template<int CT, int DEPTH, int MODE>
__global__ __launch_bounds__(128) void k_mconv(
        const unsigned short* __restrict__ Xp,
        const unsigned short* __restrict__ Wb,
        const float* __restrict__ bias,
        int nchunks, int ch_base,
        unsigned short* __restrict__ Ydst,
        float* __restrict__ outf,
        const float* __restrict__ flw)
{
    __shared__ unsigned short slab[13824]; // 4*6*18*32
    const int tid = threadIdx.x;
    const int bid0 = blockIdx.x;
    const int bid = (bid0 & 7)*108 + (bid0 >> 3);   // grid 864 = 8*108, bijective
    const int xt = bid % 3, yt = (bid/3) % 12, zt = bid / 36;
    const int x0 = xt*16, y0 = yt*4, z0 = zt*2;
    const int lane = tid & 63, w = tid >> 6;
    const int lx = lane & 15, kb = lane >> 4;

    int voff[14];
    #pragma unroll
    for (int i=0;i<14;i++){
        int u = tid + i*128;
        int p = u >> 2, q = u & 3;
        int sx = p % 18; int pr = p / 18; int sy = pr % 6; int sz = pr / 6;
        sz = min(sz, 3);
        voff[i] = ((z0+sz)*PPL + (y0+sy)*50 + (x0+sx))*CST + q*8;
    }

    float4v acc[4][CT];
    #pragma unroll
    for (int vt=0; vt<4; vt++)
        #pragma unroll
        for (int ct=0; ct<CT; ct++)
            acc[vt][ct] = (float4v){0.f,0.f,0.f,0.f};

    const unsigned short* wl = Wb + (size_t)lane*8;
    const int gmax = nchunks*27 - 1;
    short8v a[DEPTH][CT];
    #pragma unroll
    for (int d=0; d<DEPTH-1; d++)
        #pragma unroll
        for (int ct=0; ct<CT; ct++)
            a[d][ct] = *(const short8v*)(wl + (size_t)min(d,gmax)*(CT*512) + (size_t)ct*512);

    for (int chunk=0; chunk<nchunks; chunk++){
        const int cb = ch_base + chunk*32;
        __syncthreads();
        #pragma unroll
        for (int i=0;i<14;i++){
            int u = tid + i*128;
            if (i < 13 || u < 1728){
                const unsigned short* g = Xp + voff[i] + cb;
                __builtin_amdgcn_global_load_lds(
                    (const __attribute__((address_space(1))) void*)g,
                    (__attribute__((address_space(3))) void*)(slab + (size_t)u*8),
                    16, 0, 0);
            }
        }
        __syncthreads();

        const int gb = chunk*27;
        #pragma unroll
        for (int dz=0; dz<3; dz++){
            #pragma unroll
            for (int dxx=0; dxx<3; dxx++){
                short8v brow[6];
                #pragma unroll
                for (int yi=0; yi<6; yi++)
                    brow[yi] = *(const short8v*)(slab
                        + (size_t)((((w+dz)*6 + yi)*18 + dxx + lx)*32 + kb*8));
                #pragma unroll
                for (int dyy=0; dyy<3; dyy++){
                    const int t = dz*9 + dxx*3 + dyy;
                    {
                        int g2 = gb + t + (DEPTH-1); g2 = min(g2, gmax);
                        #pragma unroll
                        for (int ct=0; ct<CT; ct++)
                            a[(t+DEPTH-1)%DEPTH][ct] = *(const short8v*)(wl
                                + (size_t)g2*(CT*512) + (size_t)ct*512);
                    }
                    __builtin_amdgcn_s_setprio(1);
                    #pragma unroll
                    for (int vt=0; vt<4; vt++)
                        #pragma unroll
                        for (int ct=0; ct<CT; ct++)
                            acc[vt][ct] = __builtin_amdgcn_mfma_f32_16x16x32_bf16(
                                              a[t%DEPTH][ct], brow[vt+dyy], acc[vt][ct], 0, 0, 0);
                    __builtin_amdgcn_s_setprio(0);
                }
            }
        }
    }

    const int x = x0 + lx, z = z0 + w;
    #pragma unroll
    for (int vt=0; vt<4; vt++){
        const int y = y0 + vt;
        const size_t pvox = (size_t)((z+1)*PPL + (y+1)*50 + (x+1))*CST;
        const int vi = (z*SD + y)*SD + x;
        #pragma unroll
        for (int ct=0; ct<CT; ct++){
            if (MODE == 2){
                #pragma unroll
                for (int r=0; r<4; r++){
                    const int co = ct*16 + kb*4 + r;
                    if (co < 3){
                        float vv = acc[vt][ct][r] + bias[co];
                        outf[(size_t)co*VOX + vi] = flw[(size_t)co*VOX + vi] + vv;
                    }
                }
            } else {
                const int co0 = ct*16 + kb*4;
                short4v s4;
                #pragma unroll
                for (int r=0; r<4; r++){
                    float vv = acc[vt][ct][r] + bias[co0+r];
                    float o = lrelu(vv, 0.02f);
                    s4[r] = (short)f2bf(o);
                    if (MODE == 1)
                        outf[(size_t)(co0+r)*VOX + vi] = o;
                }
                *(short4v*)(Ydst + pvox + co0) = s4;
            }
        }
    }
}

extern "C" void kernel_launch(void* const* d_in, const int* in_sizes, int n_in,
                              void* d_out, int out_size, void* d_ws, size_t ws_size,
                              hipStream_t stream) {
    const float* moving  = (const float*)d_in[0];
    const float* fixd    = (const float*)d_in[1];
    const float* flow    = (const float*)d_in[2];
    const float* context = (const float*)d_in[3];
    const float* w0 = (const float*)d_in[4];  const float* b0 = (const float*)d_in[5];
    const float* w1 = (const float*)d_in[6];  const float* b1 = (const float*)d_in[7];
    const float* w2 = (const float*)d_in[8];  const float* b2 = (const float*)d_in[9];
    const float* w3 = (const float*)d_in[10]; const float* b3 = (const float*)d_in[11];
    const float* w4 = (const float*)d_in[12]; const float* b4 = (const float*)d_in[13];

    char* ws = (char*)d_ws;
    unsigned short* Xp    = (unsigned short*)ws;                  // 88.0 MB padded bf16, ch-last
    unsigned short* WARPB = (unsigned short*)(ws + XPBYTES);      // 16*VOX bf16 = 3.54 MB
    float* PART  = (float*)(ws + XPBYTES + 3538944ull);           // 4*432 f32
    float* STATS = (float*)(ws + XPBYTES + 3538944ull + 8192ull);
    unsigned short* Wb0 = (unsigned short*)(ws + XPBYTES + 3538944ull + 9216ull);
    unsigned short* Wb1 = Wb0 + (size_t)331776;   // 6*27*4*512
    unsigned short* Wb2 = Wb1 + (size_t)331776;   // 8*27*3*512
    unsigned short* Wb3 = Wb2 + (size_t)248832;   // 9*27*2*512
    unsigned short* Wb4 = Wb3 + (size_t)138240;   // 10*27*1*512

    float* ctx_out  = (float*)d_out;                  // 16*VOX
    float* flow_out = (float*)d_out + (size_t)16*VOX; // 3*VOX

    k_warp_prep<<<921,256,0,stream>>>(moving, fixd, flow, context, WARPB, PART, Xp);
    k_stats<<<1,256,0,stream>>>(PART, STATS);
    k_cv<<<432,256,0,stream>>>(fixd, WARPB, STATS, Xp);
    k_wb_all<<<4158,256,0,stream>>>(w0, w1, w2, w3, w4, Wb0, Wb1, Wb2, Wb3, Wb4);

    // Per-CT ring-depth law: D3 for CT>=3 (R11/R13), D9 for CT<=2 (R11)
    k_mconv<4,3,0><<<864,128,0,stream>>>(Xp, Wb0, b0, 6,  0,   Xp+176, nullptr, nullptr);
    k_mconv<3,3,0><<<864,128,0,stream>>>(Xp, Wb1, b1, 8,  0,   Xp+240, nullptr, nullptr);
    k_mconv<2,9,0><<<864,128,0,stream>>>(Xp, Wb2, b2, 9,  0,   Xp+288, nullptr, nullptr);
    k_mconv<1,9,1><<<864,128,0,stream>>>(Xp, Wb3, b3, 10, 0,   Xp+320, ctx_out, nullptr);
    k_mconv<1,3,2><<<864,128,0,stream>>>(Xp, Wb4, b4, 1,  320, Xp,     flow_out, flow);
}